// Round 5
// baseline (48.444 us; speedup 1.0000x reference)
//
#include <hip/hip_runtime.h>
#include <math.h>

#define LOG2E 1.4426950408889634f
#define NSLOT 512   // LDS accumulator slots per block (block spans ~16 atoms)
#define EPB   1024  // edges per block (256 threads x 4 edges)

// consts layout (7 floats):
//   [0]    softmax coeff of the min-exponent term (its exp factor == 1)
//   [1..3] softmax coeffs of the other 3 terms
//   [4..6] (e2_k - e2_min) / |a|   (log2-domain exponent deltas, pre-divided)
//
// tab_i[n] = (za, 0.5*z*atom_mask)   i-side payload (mask+0.5 folded in)
// tab_j[n] = (za, z)                 j-side payload

// ---------------------------------------------------------------------------
// Kernel 1: per-atom tables, zero output, scalar consts.
// ---------------------------------------------------------------------------
__global__ __launch_bounds__(256) void zbl_prep_kernel(
    const float* __restrict__ z, const float* __restrict__ amask,
    const float* __restrict__ a_coef, const float* __restrict__ a_exp,
    const float* __restrict__ phi_c, const float* __restrict__ phi_e,
    float2* __restrict__ tab_i, float2* __restrict__ tab_j,
    float* __restrict__ out, float* __restrict__ consts, int n_atoms) {
  int n = blockIdx.x * blockDim.x + threadIdx.x;
  if (n < n_atoms) {
    float zi = z[n];                       // in [1, 94] -> log safe
    float ae = fabsf(a_exp[0]);
    float za = __builtin_amdgcn_exp2f(ae * __builtin_amdgcn_logf(zi));
    tab_i[n] = make_float2(za, 0.5f * zi * amask[n]);
    tab_j[n] = make_float2(za, zi);
    out[n] = 0.0f;
  }
  if (blockIdx.x == 0 && threadIdx.x == 0) {
    float c[4], e2[4];
    float m = -1e30f;
    for (int k = 0; k < 4; ++k) { c[k] = fabsf(phi_c[k]); m = fmaxf(m, c[k]); }
    float s = 0.0f;
    for (int k = 0; k < 4; ++k) { c[k] = expf(c[k] - m); s += c[k]; }
    for (int k = 0; k < 4; ++k) c[k] /= s;
    int kmin = 0;
    for (int k = 0; k < 4; ++k) {
      e2[k] = fabsf(phi_e[k]) * LOG2E;
      if (e2[k] < e2[kmin]) kmin = k;
    }
    float inv_a = 1.0f / fabsf(a_coef[0]);
    consts[0] = c[kmin];
    int p = 1;
    for (int k = 0; k < 4; ++k) {
      if (k != kmin) {
        consts[p] = c[k];
        consts[3 + p] = (e2[k] - e2[kmin]) * inv_a;
        ++p;
      }
    }
  }
}

// ---------------------------------------------------------------------------
// Per-edge math (verified R3/R4), tables pre-gathered by caller.
// ti = (za_i, 0.5*z_i*amask_i), tj = (za_j, z_j)
// ---------------------------------------------------------------------------
__device__ __forceinline__ float zbl_edge_value(
    float dx, float dy, float dz, float2 ti, float2 tj, float bm,
    float c0, float c1, float c2, float c3,
    float dd1, float dd2, float dd3) {
  float n2 = fmaxf(dx * dx + dy * dy + dz * dz, 1e-20f);
  float r = __builtin_amdgcn_rsqf(n2);  // 1/d
  float d = n2 * r;                     // d = sqrt(n2)
  // smooth switch on [CUTON=4, CUTOFF=5]
  float x = 5.0f - d;
  float poly = ((6.0f * x - 15.0f) * x + 10.0f) * x * x * x;
  float sw = (d < 4.0f) ? 1.0f : ((d >= 5.0f) ? 0.0f : poly);
  float q = d * fmaxf(ti.x + tj.x, 1e-10f);
  // phi = c_min + sum_k c_k * 2^(-dd_k*q)  (reference's shifted-exp quirk:
  // max_log = -e_min*arg is always the max term since arg >= 0)
  float phi = c0 + c1 * __builtin_amdgcn_exp2f(-dd1 * q)
                 + c2 * __builtin_amdgcn_exp2f(-dd2 * q)
                 + c3 * __builtin_amdgcn_exp2f(-dd3 * q);
  return ti.y * tj.y * r * fmaxf(phi, 1e-30f) * fmaxf(sw, 1e-30f) * bm;
}

// ---------------------------------------------------------------------------
// Kernel 2: block owns 1024 consecutive edges (4/thread, vectorized loads,
// all 8 table gathers hoisted before compute). In-register run merge ->
// LDS float atomics keyed relative to the block's first atom -> barrier ->
// sweep emits one global atomic per touched atom. Out-of-range keys fall
// back to global atomics, so correctness never depends on sortedness.
// atom_mask and 0.5 are pre-folded into tab_i.
// ---------------------------------------------------------------------------
__global__ __launch_bounds__(256, 8) void zbl_edge_kernel(
    const float* __restrict__ disp, const int* __restrict__ idx_i,
    const int* __restrict__ idx_j, const float* __restrict__ bmask,
    const float2* __restrict__ tab_i, const float2* __restrict__ tab_j,
    const float* __restrict__ consts, float* __restrict__ out, int n_edges) {
  __shared__ float acc[NSLOT];
  const int t = threadIdx.x;
  const long block_base = (long)blockIdx.x * EPB;

  acc[t] = 0.0f;
  acc[t + 256] = 0.0f;

  const int key_base = idx_i[block_base];  // uniform broadcast load
  const float c0 = consts[0], c1 = consts[1], c2 = consts[2], c3 = consts[3];
  const float dd1 = consts[4], dd2 = consts[5], dd3 = consts[6];

  const long L = (long)blockIdx.x * 256 + t;  // global quad id
  const long e0 = L * 4;

  int k0 = -1, k1 = -1, k2 = -1, k3 = -1;
  float v0 = 0.f, v1 = 0.f, v2 = 0.f, v3 = 0.f;

  if (e0 + 3 < (long)n_edges) {
    // -- issue index loads --
    int4 I = ((const int4*)idx_i)[L];
    int4 J = ((const int4*)idx_j)[L];
    // -- issue streaming loads (independent of I/J) --
    const float4* d4 = (const float4*)disp;
    float4 A = d4[3 * L], B = d4[3 * L + 1], Cc = d4[3 * L + 2];
    float4 BM = ((const float4*)bmask)[L];
    // -- issue all 8 table gathers together (MLP) --
    float2 ti0 = tab_i[I.x], ti1 = tab_i[I.y], ti2 = tab_i[I.z], ti3 = tab_i[I.w];
    float2 tj0 = tab_j[J.x], tj1 = tab_j[J.y], tj2 = tab_j[J.z], tj3 = tab_j[J.w];
    // -- compute 4 edges --
    // disp unpack: e0=(A.x,A.y,A.z) e1=(A.w,B.x,B.y) e2=(B.z,B.w,Cc.x)
    //              e3=(Cc.y,Cc.z,Cc.w)
    v0 = zbl_edge_value(A.x, A.y, A.z, ti0, tj0, BM.x, c0, c1, c2, c3, dd1, dd2, dd3);
    v1 = zbl_edge_value(A.w, B.x, B.y, ti1, tj1, BM.y, c0, c1, c2, c3, dd1, dd2, dd3);
    v2 = zbl_edge_value(B.z, B.w, Cc.x, ti2, tj2, BM.z, c0, c1, c2, c3, dd1, dd2, dd3);
    v3 = zbl_edge_value(Cc.y, Cc.z, Cc.w, ti3, tj3, BM.w, c0, c1, c2, c3, dd1, dd2, dd3);
    k0 = I.x; k1 = I.y; k2 = I.z; k3 = I.w;
  } else {
    long e;
    e = e0;
    if (e < (long)n_edges) {
      int i = idx_i[e], j = idx_j[e];
      v0 = zbl_edge_value(disp[3 * e], disp[3 * e + 1], disp[3 * e + 2],
                          tab_i[i], tab_j[j], bmask[e], c0, c1, c2, c3, dd1, dd2, dd3);
      k0 = i;
    }
    e = e0 + 1;
    if (e < (long)n_edges) {
      int i = idx_i[e], j = idx_j[e];
      v1 = zbl_edge_value(disp[3 * e], disp[3 * e + 1], disp[3 * e + 2],
                          tab_i[i], tab_j[j], bmask[e], c0, c1, c2, c3, dd1, dd2, dd3);
      k1 = i;
    }
    e = e0 + 2;
    if (e < (long)n_edges) {
      int i = idx_i[e], j = idx_j[e];
      v2 = zbl_edge_value(disp[3 * e], disp[3 * e + 1], disp[3 * e + 2],
                          tab_i[i], tab_j[j], bmask[e], c0, c1, c2, c3, dd1, dd2, dd3);
      k2 = i;
    }
    e = e0 + 3;
    if (e < (long)n_edges) {
      int i = idx_i[e], j = idx_j[e];
      v3 = zbl_edge_value(disp[3 * e], disp[3 * e + 1], disp[3 * e + 2],
                          tab_i[i], tab_j[j], bmask[e], c0, c1, c2, c3, dd1, dd2, dd3);
      k3 = i;
    }
  }

  __syncthreads();  // LDS zeroing complete before any atomics land

  auto flush = [&](int key, float s) {
    if (key < 0) return;
    int slot = key - key_base;
    if ((unsigned)slot < (unsigned)NSLOT) atomicAdd(&acc[slot], s);
    else atomicAdd(&out[key], s);  // amask already folded into tab_i
  };

  // in-register merge of equal-adjacent keys (sorted => ~1 run per thread)
  {
    int cur = k0;
    float s = v0;
    if (k1 == cur) s += v1; else { flush(cur, s); cur = k1; s = v1; }
    if (k2 == cur) s += v2; else { flush(cur, s); cur = k2; s = v2; }
    if (k3 == cur) s += v3; else { flush(cur, s); cur = k3; s = v3; }
    flush(cur, s);
  }

  __syncthreads();  // all LDS accumulation done

  #pragma unroll
  for (int s2 = 0; s2 < NSLOT; s2 += 256) {
    float val = acc[t + s2];
    if (val != 0.0f) {  // zero slots contribute nothing; skip is exact
      atomicAdd(&out[key_base + t + s2], val);
    }
  }
}

extern "C" void kernel_launch(void* const* d_in, const int* in_sizes, int n_in,
                              void* d_out, int out_size, void* d_ws,
                              size_t ws_size, hipStream_t stream) {
  const float* atomic_numbers = (const float*)d_in[0];
  const float* disp           = (const float*)d_in[1];
  const int*   idx_i          = (const int*)d_in[2];
  const int*   idx_j          = (const int*)d_in[3];
  const float* atom_mask      = (const float*)d_in[4];
  // d_in[5] = batch_segments (unused), d_in[7] = batch_size (unused)
  const float* bmask          = (const float*)d_in[6];
  const float* a_coef         = (const float*)d_in[8];
  const float* a_exp          = (const float*)d_in[9];
  const float* phi_c          = (const float*)d_in[10];
  const float* phi_e          = (const float*)d_in[11];

  int n_atoms = in_sizes[0];
  int n_edges = in_sizes[2];

  float* out = (float*)d_out;
  float2* tab_i = (float2*)d_ws;
  float2* tab_j = (float2*)((char*)d_ws + (size_t)n_atoms * sizeof(float2));
  float* consts = (float*)((char*)d_ws + 2 * (size_t)n_atoms * sizeof(float2));

  int atom_blocks = (n_atoms + 255) / 256;
  int edge_blocks = (int)(((long)n_edges + EPB - 1) / EPB);

  zbl_prep_kernel<<<atom_blocks, 256, 0, stream>>>(
      atomic_numbers, atom_mask, a_coef, a_exp, phi_c, phi_e, tab_i, tab_j,
      out, consts, n_atoms);
  zbl_edge_kernel<<<edge_blocks, 256, 0, stream>>>(
      disp, idx_i, idx_j, bmask, tab_i, tab_j, consts, out, n_edges);
}